// Round 6
// baseline (496.402 us; speedup 1.0000x reference)
//
#include <hip/hip_runtime.h>

#define DIM   2048
#define NEXP  64
#define NTOK  32768
#define DC    64                  // d-chunk per stage
#define NC    (DIM / DC)          // 32 chunks
#define TB    128                 // tokens per block
#define NBLK  (NTOK / TB)         // 256 blocks = exactly 1/CU
#define XSTR  164                 // floats per xT d-row (8 grp*20 + pad; shifts banks 4/d)
#define XOFF  (DC * NEXP)         // W region first: 4096 floats
#define BUFF  (XOFF + DC * XSTR)  // 14592 floats per buffer
#define T1OFF (2 * BUFF)          // 29184: second reduction tile
#define DOFF  (T1OFF + TB * NEXP) // 37376: denom scratch
#define LDSF  (DOFF + NEXP)       // 37440 floats = 146.25 KB (fits 160K/CU)

typedef __attribute__((address_space(1))) const void gvoid_t;
typedef __attribute__((address_space(3))) void lvoid_t;
#define GLDS16(g, l) __builtin_amdgcn_global_load_lds((gvoid_t*)(g), (lvoid_t*)(l), 16, 0, 0)

__global__ void zero_denom_kernel(float* __restrict__ denom) {
    denom[threadIdx.x] = 0.0f;
}

// acc[i][0..7] += xs * {wa,wc}
#define FMA_ROW(i, xs)                         \
    acc[i][0] = fmaf((xs), wa.x, acc[i][0]);   \
    acc[i][1] = fmaf((xs), wa.y, acc[i][1]);   \
    acc[i][2] = fmaf((xs), wa.z, acc[i][2]);   \
    acc[i][3] = fmaf((xs), wa.w, acc[i][3]);   \
    acc[i][4] = fmaf((xs), wc.x, acc[i][4]);   \
    acc[i][5] = fmaf((xs), wc.y, acc[i][5]);   \
    acc[i][6] = fmaf((xs), wc.z, acc[i][6]);   \
    acc[i][7] = fmaf((xs), wc.w, acc[i][7]);

__global__ __launch_bounds__(256, 1)
void gate_kernel(const float* __restrict__ x, const float* __restrict__ w,
                 const float* __restrict__ b, float* __restrict__ out,
                 float* __restrict__ denom)
{
    __shared__ float lds[LDSF];

    const int tid  = threadIdx.x;
    const int lane = tid & 63;
    const int wv   = tid >> 6;
    const int tg   = lane >> 3;     // token group: lane owns tokens tg*16..+15
    const int eg   = lane & 7;      // expert group: lane owns experts eg*8..+7
    const int tok0 = blockIdx.x * TB;

    if (tid < NEXP) lds[DOFF + tid] = 0.0f;

    // ---- x staging: 2048 f4/chunk, 8 per thread; fi = i*256+tid ->
    //      token = fi>>4 (16 f4 per token-chunk-row), d0 = (fi&15)*4. Coalesced.
    const float* xsrc[8];
    int xwb[8];
#pragma unroll
    for (int i = 0; i < 8; ++i) {
        const int fi = i * 256 + tid;
        const int t  = fi >> 4;
        const int d0 = (fi & 15) * 4;
        xsrc[i] = x + (size_t)(tok0 + t) * DIM + d0;
        xwb[i]  = XOFF + d0 * XSTR + (t >> 4) * 20 + (t & 15);
    }

    auto stageW = [&](int bsel, int c) {
        const float* wsrc = w + (size_t)c * (DC * NEXP);
        float* base = lds + bsel * BUFF;
#pragma unroll
        for (int i = 0; i < 4; ++i) {
            const int of = (wv * 4 + i) * 256 + lane * 4;   // linear in lane
            GLDS16(wsrc + of, base + of);
        }
    };
    auto loadX = [&](float4* xf, int c) {
#pragma unroll
        for (int i = 0; i < 8; ++i) xf[i] = *(const float4*)(xsrc[i] + c * DC);
    };
    auto writeX = [&](const float4* xf, int bsel) {
        float* base = lds + bsel * BUFF;
#pragma unroll
        for (int i = 0; i < 8; ++i) {
            base[xwb[i]           ] = xf[i].x;   // xT[d][t], bank-shifted rows
            base[xwb[i] + XSTR    ] = xf[i].y;
            base[xwb[i] + 2 * XSTR] = xf[i].z;
            base[xwb[i] + 3 * XSTR] = xf[i].w;
        }
    };

    float acc[16][8];
#pragma unroll
    for (int i = 0; i < 16; ++i)
#pragma unroll
        for (int j = 0; j < 8; ++j) acc[i][j] = 0.0f;

    float4 xf[8];
    stageW(0, 0); loadX(xf, 0); writeX(xf, 0);
    __syncthreads();

    const int wv16 = wv * 16;   // wave's d-slice within each chunk

    for (int c = 0; c < NC; ++c) {
        const int cur = c & 1;
        if (c + 1 < NC) { stageW(cur ^ 1, c + 1); loadX(xf, c + 1); }

        const float* wrow = lds + cur * BUFF + wv16 * 64;          // W[d][e]
        const float* xrow = lds + cur * BUFF + XOFF + wv16 * XSTR; // xT[d][g20+r]
#pragma unroll
        for (int dd = 0; dd < 16; ++dd) {
            const float4 xa0 = *(const float4*)(xrow + dd * XSTR + tg * 20);
            const float4 xa1 = *(const float4*)(xrow + dd * XSTR + tg * 20 + 4);
            const float4 xa2 = *(const float4*)(xrow + dd * XSTR + tg * 20 + 8);
            const float4 xa3 = *(const float4*)(xrow + dd * XSTR + tg * 20 + 12);
            const float4 wa  = *(const float4*)(wrow + dd * 64 + eg * 8);
            const float4 wc  = *(const float4*)(wrow + dd * 64 + eg * 8 + 4);
            FMA_ROW( 0, xa0.x) FMA_ROW( 1, xa0.y) FMA_ROW( 2, xa0.z) FMA_ROW( 3, xa0.w)
            FMA_ROW( 4, xa1.x) FMA_ROW( 5, xa1.y) FMA_ROW( 6, xa1.z) FMA_ROW( 7, xa1.w)
            FMA_ROW( 8, xa2.x) FMA_ROW( 9, xa2.y) FMA_ROW(10, xa2.z) FMA_ROW(11, xa2.w)
            FMA_ROW(12, xa3.x) FMA_ROW(13, xa3.y) FMA_ROW(14, xa3.z) FMA_ROW(15, xa3.w)
        }

        if (c + 1 < NC) writeX(xf, cur ^ 1);
        __syncthreads();
    }

    // ---- deterministic cross-wave k-reduction (buffers dead; T0 at 0, T1 at T1OFF)
    {
        // pass 1: waves 0,1 store their partial 128x64 tiles
        if (wv < 2) {
            float* T = lds + (wv ? T1OFF : 0);
#pragma unroll
            for (int i = 0; i < 16; ++i) {
                float4 lo = {acc[i][0], acc[i][1], acc[i][2], acc[i][3]};
                float4 hi = {acc[i][4], acc[i][5], acc[i][6], acc[i][7]};
                *(float4*)(T + (tg * 16 + i) * 64 + eg * 8)     = lo;
                *(float4*)(T + (tg * 16 + i) * 64 + eg * 8 + 4) = hi;
            }
        }
        __syncthreads();
        // pass 2: waves 2,3 accumulate into T0,T1
        if (wv >= 2) {
            float* T = lds + ((wv == 2) ? 0 : T1OFF);
#pragma unroll
            for (int i = 0; i < 16; ++i) {
                float4* plo = (float4*)(T + (tg * 16 + i) * 64 + eg * 8);
                float4* phi = (float4*)(T + (tg * 16 + i) * 64 + eg * 8 + 4);
                float4 lo = *plo, hi = *phi;
                lo.x += acc[i][0]; lo.y += acc[i][1]; lo.z += acc[i][2]; lo.w += acc[i][3];
                hi.x += acc[i][4]; hi.y += acc[i][5]; hi.z += acc[i][6]; hi.w += acc[i][7];
                *plo = lo; *phi = hi;
            }
        }
        __syncthreads();
        // pass 3: T0 += T1 (wave wv handles its 32-token slice)
        {
            float*       t0 = lds + wv * 2048;
            const float* t1 = lds + T1OFF + wv * 2048;
#pragma unroll
            for (int q = 0; q < 8; ++q) {
                const int idx = q * 256 + lane * 4;
                float4 a = *(const float4*)(t0 + idx);
                const float4 bb = *(const float4*)(t1 + idx);
                a.x += bb.x; a.y += bb.y; a.z += bb.z; a.w += bb.w;
                *(float4*)(t0 + idx) = a;
            }
        }
        __syncthreads();
    }

    // ---- epilogue: wave wv owns tokens [wv*32, wv*32+32), lane = expert
    const float bias = b[lane];
#pragma unroll 4
    for (int tt = 0; tt < 32; ++tt) {
        const int t = wv * 32 + tt;
        float v = bias + lds[t * 64 + lane];

        // wave argmax, FIRST index on ties (matches jnp.argmax)
        float m = v; int mi = lane;
#pragma unroll
        for (int off = 32; off > 0; off >>= 1) {
            float om = __shfl_xor(m, off);
            int   oi = __shfl_xor(mi, off);
            if (om > m || (om == m && oi < mi)) { m = om; mi = oi; }
        }
        float s = __expf(v - m);
#pragma unroll
        for (int off = 32; off > 0; off >>= 1) s += __shfl_xor(s, off);
        const float g = 1.0f / s;   // top-1 gate = exp(0)/sum

        out[(size_t)(tok0 + t) * NEXP + lane] = (lane == mi) ? g : 0.0f;
        if (lane == mi) atomicAdd(&lds[DOFF + lane], g);
    }

    __syncthreads();
    if (tid < NEXP) atomicAdd(&denom[tid], lds[DOFF + tid]);
}

// out[n,e] *= capacity / (denom[e] + eps); zeros stay zero (branch-free)
__global__ __launch_bounds__(256)
void scale_kernel(float* __restrict__ out, const float* __restrict__ denom)
{
    __shared__ float sc[NEXP];
    if (threadIdx.x < NEXP)
        sc[threadIdx.x] = (float)NTOK / (denom[threadIdx.x] + 1e-6f);
    __syncthreads();

    const size_t i = (size_t)blockIdx.x * blockDim.x + threadIdx.x; // float4 idx
    float4 v = ((const float4*)out)[i];
    const int e0 = (int)((i * 4) & (NEXP - 1));
    v.x *= sc[e0]; v.y *= sc[e0 + 1]; v.z *= sc[e0 + 2]; v.w *= sc[e0 + 3];
    ((float4*)out)[i] = v;
}

extern "C" void kernel_launch(void* const* d_in, const int* in_sizes, int n_in,
                              void* d_out, int out_size, void* d_ws, size_t ws_size,
                              hipStream_t stream) {
    const float* x = (const float*)d_in[0];
    const float* w = (const float*)d_in[1];
    const float* b = (const float*)d_in[2];
    float* out   = (float*)d_out;
    float* denom = (float*)d_ws;   // 64 floats

    zero_denom_kernel<<<1, NEXP, 0, stream>>>(denom);
    gate_kernel<<<NBLK, 256, 0, stream>>>(x, w, b, out, denom);
    scale_kernel<<<(NTOK * NEXP / 4) / 256, 256, 0, stream>>>(out, denom);
}

// Round 7
// 117.686 us; speedup vs baseline: 4.2180x; 4.2180x over previous
//
#include <hip/hip_runtime.h>

#define DIM   2048
#define NEXP  64
#define NTOK  32768
#define KC    32               // k per chunk = one MFMA k-step
#define NC    (DIM / KC)       // 64 chunks
#define TB    128              // tokens per block (4 waves x 32)
#define NBLK  (NTOK / TB)      // 256 blocks
#define WFOFF 1024             // byte offset of w-fragments inside d_ws

typedef __attribute__((ext_vector_type(8))) short bf16x8;
typedef __attribute__((ext_vector_type(4))) float f32x4;

// round-to-nearest-even fp32 -> bf16; returns the fp32 value of the bf16
__device__ __forceinline__ float rne_split(float v, short& h) {
    unsigned u = __builtin_bit_cast(unsigned, v);
    unsigned r = (u + 0x7fffu + ((u >> 16) & 1u)) & 0xffff0000u;
    h = (short)(r >> 16);
    return __builtin_bit_cast(float, r);
}

// split 8 fp32 (two float4) into 3 bf16x8 fragment levels (hi/mid/lo)
__device__ __forceinline__ void split8(const float4& a, const float4& b,
                                       bf16x8& H, bf16x8& M, bf16x8& L) {
    const float vs[8] = {a.x, a.y, a.z, a.w, b.x, b.y, b.z, b.w};
#pragma unroll
    for (int j = 0; j < 8; ++j) {
        short h, m, l;
        const float fh = rne_split(vs[j], h);
        const float e1 = vs[j] - fh;            // exact (Sterbenz)
        const float fm = rne_split(e1, m);
        const float e2 = e1 - fm;               // exact
        rne_split(e2, l);
        H[j] = h; M[j] = m; L[j] = l;
    }
}

__global__ void zero_denom_kernel(float* __restrict__ denom) {
    denom[threadIdx.x] = 0.0f;
}

// Pre-split w into B-fragment-ordered bf16 levels in d_ws.
// Unit (16B, one lane's frag): idx = ((sp*NC + ks)*4 + ni)*64 + lane
// covering B[k = ks*32 + 8*(lane>>4) + j][n = ni*16 + (lane&15)].
__global__ __launch_bounds__(256)
void wsplit_kernel(const float* __restrict__ w, bf16x8* __restrict__ wf) {
    const int tid  = blockIdx.x * 256 + threadIdx.x;   // 16384 threads
    const int lane = tid & 63;
    const int ni   = (tid >> 6) & 3;
    const int ks   = tid >> 8;
    const int n    = ni * 16 + (lane & 15);
    const int k0   = ks * KC + (lane >> 4) * 8;
    bf16x8 H, M, L;
#pragma unroll
    for (int j = 0; j < 8; ++j) {
        const float v = w[(size_t)(k0 + j) * NEXP + n];
        short h, m, l;
        const float fh = rne_split(v, h);
        const float e1 = v - fh;
        const float fm = rne_split(e1, m);
        rne_split(e1 - fm, l);
        H[j] = h; M[j] = m; L[j] = l;
    }
    wf[((size_t)(0 * NC + ks) * 4 + ni) * 64 + lane] = H;
    wf[((size_t)(1 * NC + ks) * 4 + ni) * 64 + lane] = M;
    wf[((size_t)(2 * NC + ks) * 4 + ni) * 64 + lane] = L;
}

__global__ __launch_bounds__(256)
void gate_kernel(const float* __restrict__ x, const bf16x8* __restrict__ wf,
                 const float* __restrict__ b, float* __restrict__ out,
                 float* __restrict__ denom)
{
    __shared__ float dlds[NEXP];

    const int tid  = threadIdx.x;
    const int lane = tid & 63;
    const int wv   = tid >> 6;
    const int l15  = lane & 15;
    const int l4   = lane >> 4;
    const int tok0 = blockIdx.x * TB + wv * 32;

    if (tid < NEXP) dlds[tid] = 0.0f;

    // A-side: lane's fragment k-range IS its own contiguous 32B of the row
    const float* xr0 = x + (size_t)(tok0 + l15) * DIM + l4 * 8;        // m=0
    const float* xr1 = xr0 + (size_t)16 * DIM;                          // m=1

    f32x4 acc[2][4];
#pragma unroll
    for (int mi = 0; mi < 2; ++mi)
#pragma unroll
        for (int ni = 0; ni < 4; ++ni) acc[mi][ni] = (f32x4){0.f, 0.f, 0.f, 0.f};

    auto loadx = [&](float4* xv, int c) {
        xv[0] = *(const float4*)(xr0 + c * KC);
        xv[1] = *(const float4*)(xr0 + c * KC + 4);
        xv[2] = *(const float4*)(xr1 + c * KC);
        xv[3] = *(const float4*)(xr1 + c * KC + 4);
    };
    auto compute = [&](const float4* xv, int c) {
        bf16x8 Ah0, Am0, Al0, Ah1, Am1, Al1;
        split8(xv[0], xv[1], Ah0, Am0, Al0);
        split8(xv[2], xv[3], Ah1, Am1, Al1);
#pragma unroll
        for (int ni = 0; ni < 4; ++ni) {
            const bf16x8 bh = wf[((size_t)(0 * NC + c) * 4 + ni) * 64 + lane];
            const bf16x8 bm = wf[((size_t)(1 * NC + c) * 4 + ni) * 64 + lane];
            const bf16x8 bl = wf[((size_t)(2 * NC + c) * 4 + ni) * 64 + lane];
            f32x4 a0 = acc[0][ni], a1 = acc[1][ni];
            a0 = __builtin_amdgcn_mfma_f32_16x16x32_bf16(Ah0, bh, a0, 0, 0, 0);
            a0 = __builtin_amdgcn_mfma_f32_16x16x32_bf16(Ah0, bm, a0, 0, 0, 0);
            a0 = __builtin_amdgcn_mfma_f32_16x16x32_bf16(Am0, bh, a0, 0, 0, 0);
            a0 = __builtin_amdgcn_mfma_f32_16x16x32_bf16(Ah0, bl, a0, 0, 0, 0);
            a0 = __builtin_amdgcn_mfma_f32_16x16x32_bf16(Am0, bm, a0, 0, 0, 0);
            a0 = __builtin_amdgcn_mfma_f32_16x16x32_bf16(Al0, bh, a0, 0, 0, 0);
            a1 = __builtin_amdgcn_mfma_f32_16x16x32_bf16(Ah1, bh, a1, 0, 0, 0);
            a1 = __builtin_amdgcn_mfma_f32_16x16x32_bf16(Ah1, bm, a1, 0, 0, 0);
            a1 = __builtin_amdgcn_mfma_f32_16x16x32_bf16(Am1, bh, a1, 0, 0, 0);
            a1 = __builtin_amdgcn_mfma_f32_16x16x32_bf16(Ah1, bl, a1, 0, 0, 0);
            a1 = __builtin_amdgcn_mfma_f32_16x16x32_bf16(Am1, bm, a1, 0, 0, 0);
            a1 = __builtin_amdgcn_mfma_f32_16x16x32_bf16(Al1, bh, a1, 0, 0, 0);
            acc[0][ni] = a0; acc[1][ni] = a1;
        }
    };

    float4 xa[4], xb[4];
    loadx(xa, 0);
    for (int c = 0; c < NC; c += 2) {           // ping-pong, static indexing
        loadx(xb, c + 1);
        compute(xa, c);
        if (c + 2 < NC) loadx(xa, c + 2);
        compute(xb, c + 1);
    }

    __syncthreads();   // dlds zeroed

    // epilogue: token tl = mi*16 + 4*l4 + r, experts e = 16*ni + l15
    float bias[4];
#pragma unroll
    for (int ni = 0; ni < 4; ++ni) bias[ni] = b[ni * 16 + l15];

#pragma unroll
    for (int mi = 0; mi < 2; ++mi)
#pragma unroll
        for (int r = 0; r < 4; ++r) {
            const float v0 = acc[mi][0][r] + bias[0];
            const float v1 = acc[mi][1][r] + bias[1];
            const float v2 = acc[mi][2][r] + bias[2];
            const float v3 = acc[mi][3][r] + bias[3];

            // lane-local argmax (ascending e => first-index ties)
            float lm = v0; int le = l15;
            if (v1 > lm) { lm = v1; le = l15 + 16; }
            if (v2 > lm) { lm = v2; le = l15 + 32; }
            if (v3 > lm) { lm = v3; le = l15 + 48; }
            // 16-lane group reduce (same token), first-index on ties
#pragma unroll
            for (int off = 1; off < 16; off <<= 1) {
                const float om = __shfl_xor(lm, off);
                const int   oe = __shfl_xor(le, off);
                if (om > lm || (om == lm && oe < le)) { lm = om; le = oe; }
            }
            float s = __expf(v0 - lm) + __expf(v1 - lm) +
                      __expf(v2 - lm) + __expf(v3 - lm);
#pragma unroll
            for (int off = 1; off < 16; off <<= 1) s += __shfl_xor(s, off);
            const float g = 1.0f / s;            // top-1 gate = exp(0)/sum

            const int t = tok0 + mi * 16 + 4 * l4 + r;
            float* orow = out + (size_t)t * NEXP + l15;
            orow[0]  = (le == l15     ) ? g : 0.0f;
            orow[16] = (le == l15 + 16) ? g : 0.0f;
            orow[32] = (le == l15 + 32) ? g : 0.0f;
            orow[48] = (le == l15 + 48) ? g : 0.0f;
            if (l15 == 0) atomicAdd(&dlds[le], g);
        }

    __syncthreads();
    if (tid < NEXP) atomicAdd(&denom[tid], dlds[tid]);
}

// out[n,e] *= capacity / (denom[e] + eps); zeros stay zero (branch-free)
__global__ __launch_bounds__(256)
void scale_kernel(float* __restrict__ out, const float* __restrict__ denom)
{
    __shared__ float sc[NEXP];
    if (threadIdx.x < NEXP)
        sc[threadIdx.x] = (float)NTOK / (denom[threadIdx.x] + 1e-6f);
    __syncthreads();

    const size_t i = (size_t)blockIdx.x * blockDim.x + threadIdx.x; // float4 idx
    float4 v = ((const float4*)out)[i];
    const int e0 = (int)((i * 4) & (NEXP - 1));
    v.x *= sc[e0]; v.y *= sc[e0 + 1]; v.z *= sc[e0 + 2]; v.w *= sc[e0 + 3];
    ((float4*)out)[i] = v;
}

extern "C" void kernel_launch(void* const* d_in, const int* in_sizes, int n_in,
                              void* d_out, int out_size, void* d_ws, size_t ws_size,
                              hipStream_t stream) {
    const float* x = (const float*)d_in[0];
    const float* w = (const float*)d_in[1];
    const float* b = (const float*)d_in[2];
    float*  out   = (float*)d_out;
    float*  denom = (float*)d_ws;                               // 64 floats
    bf16x8* wf    = (bf16x8*)((char*)d_ws + WFOFF);             // 768 KB frags

    zero_denom_kernel<<<1, NEXP, 0, stream>>>(denom);
    wsplit_kernel<<<64, 256, 0, stream>>>(w, wf);               // stream-ordered
    gate_kernel<<<NBLK, 256, 0, stream>>>(x, wf, b, out, denom);
    scale_kernel<<<(NTOK * NEXP / 4) / 256, 256, 0, stream>>>(out, denom);
}

// Round 8
// 116.884 us; speedup vs baseline: 4.2470x; 1.0069x over previous
//
#include <hip/hip_runtime.h>
#include <hip/hip_bf16.h>

#define DIM   2048
#define NEXP  64
#define NTOK  32768
#define KC    32               // k per chunk = one MFMA k-step
#define NC    (DIM / KC)       // 64 chunks
#define TB    64               // tokens per block (4 waves x 16)
#define NBLK  (NTOK / TB)      // 512 blocks -> 2048 waves -> 2/SIMD
#define WFOFF 1024             // byte offset of w-fragments inside d_ws

typedef __attribute__((ext_vector_type(8))) short bf16x8;
typedef __attribute__((ext_vector_type(4))) float f32x4;

// RNE fp32 -> bf16 (compiler emits v_cvt_pk_bf16_f32); returns fp32 of the bf16
__device__ __forceinline__ float rne_split(float v, short& h) {
    __hip_bfloat16 hb = __float2bfloat16(v);
    h = __builtin_bit_cast(short, hb);
    return __bfloat162float(hb);
}

// split 8 fp32 (two float4) into 3 bf16x8 levels; e-terms exact, residual ~2^-27
__device__ __forceinline__ void split8(const float4& a, const float4& b,
                                       bf16x8& H, bf16x8& M, bf16x8& L) {
    const float vs[8] = {a.x, a.y, a.z, a.w, b.x, b.y, b.z, b.w};
#pragma unroll
    for (int j = 0; j < 8; ++j) {
        short h, m, l;
        const float fh = rne_split(vs[j], h);
        const float e1 = vs[j] - fh;            // exact
        const float fm = rne_split(e1, m);
        const float e2 = e1 - fm;               // exact
        rne_split(e2, l);
        H[j] = h; M[j] = m; L[j] = l;
    }
}

__global__ void zero_denom_kernel(float* __restrict__ denom) {
    denom[threadIdx.x] = 0.0f;
}

// Pre-split w into B-fragment-ordered bf16 levels in d_ws.
// Unit (16B, one lane's frag): idx = ((sp*NC + ks)*4 + ni)*64 + lane
// covering B[k = ks*32 + 8*(lane>>4) + j][n = ni*16 + (lane&15)].
__global__ __launch_bounds__(256)
void wsplit_kernel(const float* __restrict__ w, bf16x8* __restrict__ wf) {
    const int tid  = blockIdx.x * 256 + threadIdx.x;   // 16384 threads
    const int lane = tid & 63;
    const int ni   = (tid >> 6) & 3;
    const int ks   = tid >> 8;
    const int n    = ni * 16 + (lane & 15);
    const int k0   = ks * KC + (lane >> 4) * 8;
    bf16x8 H, M, L;
#pragma unroll
    for (int j = 0; j < 8; ++j) {
        const float v = w[(size_t)(k0 + j) * NEXP + n];
        short h, m, l;
        const float fh = rne_split(v, h);
        const float e1 = v - fh;
        const float fm = rne_split(e1, m);
        rne_split(e1 - fm, l);
        H[j] = h; M[j] = m; L[j] = l;
    }
    wf[((size_t)(0 * NC + ks) * 4 + ni) * 64 + lane] = H;
    wf[((size_t)(1 * NC + ks) * 4 + ni) * 64 + lane] = M;
    wf[((size_t)(2 * NC + ks) * 4 + ni) * 64 + lane] = L;
}

__global__ __launch_bounds__(256, 2)
void gate_kernel(const float* __restrict__ x, const bf16x8* __restrict__ wf,
                 const float* __restrict__ b, float* __restrict__ out,
                 float* __restrict__ denom)
{
    __shared__ float dlds[NEXP];

    const int tid  = threadIdx.x;
    const int lane = tid & 63;
    const int wv   = tid >> 6;
    const int l15  = lane & 15;
    const int l4   = lane >> 4;
    const int tok0 = blockIdx.x * TB + wv * 16;

    if (tid < NEXP) dlds[tid] = 0.0f;

    // A-side: lane's fragment k-range is its own contiguous 32B of token row l15
    const float* xr = x + (size_t)(tok0 + l15) * DIM + l4 * 8;

    f32x4 acc[4];
#pragma unroll
    for (int ni = 0; ni < 4; ++ni) acc[ni] = (f32x4){0.f, 0.f, 0.f, 0.f};

    bf16x8 B0[12], B1[12];   // [lvl*4 + ni], double-buffered across chunks

    auto loadB = [&](bf16x8* B, int c) {
#pragma unroll
        for (int lvl = 0; lvl < 3; ++lvl)
#pragma unroll
            for (int ni = 0; ni < 4; ++ni)
                B[lvl * 4 + ni] = wf[((size_t)(lvl * NC + c) * 4 + ni) * 64 + lane];
    };
    auto mfma6 = [&](const bf16x8* B, const bf16x8& Ah, const bf16x8& Am,
                     const bf16x8& Al) {
#pragma unroll
        for (int ni = 0; ni < 4; ++ni) {
            f32x4 a = acc[ni];
            a = __builtin_amdgcn_mfma_f32_16x16x32_bf16(Ah, B[ni],     a, 0, 0, 0);
            a = __builtin_amdgcn_mfma_f32_16x16x32_bf16(Ah, B[4 + ni], a, 0, 0, 0);
            a = __builtin_amdgcn_mfma_f32_16x16x32_bf16(Am, B[ni],     a, 0, 0, 0);
            a = __builtin_amdgcn_mfma_f32_16x16x32_bf16(Ah, B[8 + ni], a, 0, 0, 0);
            a = __builtin_amdgcn_mfma_f32_16x16x32_bf16(Am, B[4 + ni], a, 0, 0, 0);
            a = __builtin_amdgcn_mfma_f32_16x16x32_bf16(Al, B[ni],     a, 0, 0, 0);
            acc[ni] = a;
        }
    };

#define LOADX(XA, XB, c) { XA = *(const float4*)(xr + (size_t)(c) * KC);      \
                           XB = *(const float4*)(xr + (size_t)(c) * KC + 4); }
// prefetch next B, split (4-chunk-old x has arrived), reload x 4 ahead, MFMA
#define STEP(XA, XB, BC, BN, c) {                                             \
        loadB(BN, ((c) + 1 < NC) ? (c) + 1 : NC - 1);                         \
        bf16x8 Ah, Am, Al; split8(XA, XB, Ah, Am, Al);                        \
        if ((c) + 4 < NC) LOADX(XA, XB, (c) + 4);                             \
        mfma6(BC, Ah, Am, Al); }

    float4 x0a, x0b, x1a, x1b, x2a, x2b, x3a, x3b;
    loadB(B0, 0);
    LOADX(x0a, x0b, 0) LOADX(x1a, x1b, 1) LOADX(x2a, x2b, 2) LOADX(x3a, x3b, 3)

    for (int c = 0; c < NC; c += 4) {
        STEP(x0a, x0b, B0, B1, c)
        STEP(x1a, x1b, B1, B0, c + 1)
        STEP(x2a, x2b, B0, B1, c + 2)
        STEP(x3a, x3b, B1, B0, c + 3)
    }

    __syncthreads();   // dlds zeroed

    // epilogue: token t = tok0 + 4*l4 + r, experts e = 16*ni + l15
    float bias[4];
#pragma unroll
    for (int ni = 0; ni < 4; ++ni) bias[ni] = b[ni * 16 + l15];

#pragma unroll
    for (int r = 0; r < 4; ++r) {
        const float v0 = acc[0][r] + bias[0];
        const float v1 = acc[1][r] + bias[1];
        const float v2 = acc[2][r] + bias[2];
        const float v3 = acc[3][r] + bias[3];

        // lane-local argmax (ascending e => first-index ties)
        float lm = v0; int le = l15;
        if (v1 > lm) { lm = v1; le = l15 + 16; }
        if (v2 > lm) { lm = v2; le = l15 + 32; }
        if (v3 > lm) { lm = v3; le = l15 + 48; }
        // 16-lane group reduce (same token), first-index on ties
#pragma unroll
        for (int off = 1; off < 16; off <<= 1) {
            const float om = __shfl_xor(lm, off);
            const int   oe = __shfl_xor(le, off);
            if (om > lm || (om == lm && oe < le)) { lm = om; le = oe; }
        }
        float s = __expf(v0 - lm) + __expf(v1 - lm) +
                  __expf(v2 - lm) + __expf(v3 - lm);
#pragma unroll
        for (int off = 1; off < 16; off <<= 1) s += __shfl_xor(s, off);
        const float g = 1.0f / s;            // top-1 gate = exp(0)/sum

        const int t = tok0 + 4 * l4 + r;
        float* orow = out + (size_t)t * NEXP + l15;
        orow[0]  = (le == l15     ) ? g : 0.0f;
        orow[16] = (le == l15 + 16) ? g : 0.0f;
        orow[32] = (le == l15 + 32) ? g : 0.0f;
        orow[48] = (le == l15 + 48) ? g : 0.0f;
        if (l15 == 0) atomicAdd(&dlds[le], g);
    }

    __syncthreads();
    if (tid < NEXP) atomicAdd(&denom[tid], dlds[tid]);
}

// out[n,e] *= capacity / (denom[e] + eps); zeros stay zero (branch-free)
__global__ __launch_bounds__(256)
void scale_kernel(float* __restrict__ out, const float* __restrict__ denom)
{
    __shared__ float sc[NEXP];
    if (threadIdx.x < NEXP)
        sc[threadIdx.x] = (float)NTOK / (denom[threadIdx.x] + 1e-6f);
    __syncthreads();

    const size_t i = (size_t)blockIdx.x * blockDim.x + threadIdx.x; // float4 idx
    float4 v = ((const float4*)out)[i];
    const int e0 = (int)((i * 4) & (NEXP - 1));
    v.x *= sc[e0]; v.y *= sc[e0 + 1]; v.z *= sc[e0 + 2]; v.w *= sc[e0 + 3];
    ((float4*)out)[i] = v;
}

extern "C" void kernel_launch(void* const* d_in, const int* in_sizes, int n_in,
                              void* d_out, int out_size, void* d_ws, size_t ws_size,
                              hipStream_t stream) {
    const float* x = (const float*)d_in[0];
    const float* w = (const float*)d_in[1];
    const float* b = (const float*)d_in[2];
    float*  out   = (float*)d_out;
    float*  denom = (float*)d_ws;                               // 64 floats
    bf16x8* wf    = (bf16x8*)((char*)d_ws + WFOFF);             // 768 KB frags

    zero_denom_kernel<<<1, NEXP, 0, stream>>>(denom);
    wsplit_kernel<<<64, 256, 0, stream>>>(w, wf);               // stream-ordered
    gate_kernel<<<NBLK, 256, 0, stream>>>(x, wf, b, out, denom);
    scale_kernel<<<(NTOK * NEXP / 4) / 256, 256, 0, stream>>>(out, denom);
}

// Round 9
// 82.203 us; speedup vs baseline: 6.0387x; 1.4219x over previous
//
#include <hip/hip_runtime.h>
#include <hip/hip_bf16.h>

#define DIM   2048
#define NEXP  64
#define NTOK  32768
#define KC    32               // k per chunk = one MFMA k-step
#define NC    (DIM / KC)       // 64 chunks
#define NG    (NC / 2)         // 32 groups of 2 chunks
#define TB    64               // tokens per block (4 waves x 16)
#define NBLK  (NTOK / TB)      // 512 blocks -> 2 blocks/CU
#define WFOFF 1024             // byte offset of w-fragments inside d_ws
#define CH_FRAGS 12            // 3 levels x 4 ni, 16B each per lane
#define CH_BYTES (CH_FRAGS * 64 * 16)   // 12288 per chunk
#define GRP_BYTES (2 * CH_BYTES)        // 24576 per 2-chunk group

typedef __attribute__((ext_vector_type(8))) short bf16x8;
typedef __attribute__((ext_vector_type(4))) float f32x4;

typedef __attribute__((address_space(1))) const void gvoid_t;
typedef __attribute__((address_space(3))) void lvoid_t;
#define GLDS16(g, l) __builtin_amdgcn_global_load_lds((gvoid_t*)(g), (lvoid_t*)(l), 16, 0, 0)

// RNE fp32 -> bf16; returns fp32 value of the bf16 (splits are exact diffs)
__device__ __forceinline__ float rne_split(float v, short& h) {
    __hip_bfloat16 hb = __float2bfloat16(v);
    h = __builtin_bit_cast(short, hb);
    return __bfloat162float(hb);
}

__device__ __forceinline__ void split8(const float4& a, const float4& b,
                                       bf16x8& H, bf16x8& M, bf16x8& L) {
    const float vs[8] = {a.x, a.y, a.z, a.w, b.x, b.y, b.z, b.w};
#pragma unroll
    for (int j = 0; j < 8; ++j) {
        short h, m, l;
        const float fh = rne_split(vs[j], h);
        const float e1 = vs[j] - fh;            // exact
        const float fm = rne_split(e1, m);
        const float e2 = e1 - fm;               // exact
        rne_split(e2, l);
        H[j] = h; M[j] = m; L[j] = l;
    }
}

__global__ void zero_denom_kernel(float* __restrict__ denom) {
    denom[threadIdx.x] = 0.0f;
}

// Pre-split w into CHUNK-MAJOR fragment order:
// unit idx = ((ks*3 + lvl)*4 + ni)*64 + lane  -> 12KB contiguous per chunk,
// covering B[k = ks*32 + 8*(lane>>4) + j][n = ni*16 + (lane&15)].
__global__ __launch_bounds__(256)
void wsplit_kernel(const float* __restrict__ w, bf16x8* __restrict__ wf) {
    const int tid  = blockIdx.x * 256 + threadIdx.x;   // 16384 threads
    const int lane = tid & 63;
    const int ni   = (tid >> 6) & 3;
    const int ks   = tid >> 8;
    const int n    = ni * 16 + (lane & 15);
    const int k0   = ks * KC + (lane >> 4) * 8;
    bf16x8 H, M, L;
#pragma unroll
    for (int j = 0; j < 8; ++j) {
        const float v = w[(size_t)(k0 + j) * NEXP + n];
        short h, m, l;
        const float fh = rne_split(v, h);
        const float e1 = v - fh;
        const float fm = rne_split(e1, m);
        rne_split(e1 - fm, l);
        H[j] = h; M[j] = m; L[j] = l;
    }
    wf[((size_t)(ks * 3 + 0) * 4 + ni) * 64 + lane] = H;
    wf[((size_t)(ks * 3 + 1) * 4 + ni) * 64 + lane] = M;
    wf[((size_t)(ks * 3 + 2) * 4 + ni) * 64 + lane] = L;
}

__global__ __launch_bounds__(256, 2)
void gate_kernel(const float* __restrict__ x, const bf16x8* __restrict__ wf,
                 const float* __restrict__ b, float* __restrict__ out,
                 float* __restrict__ denom)
{
    __shared__ bf16x8 Blds[2][2][CH_FRAGS * 64];   // 48 KB, double-buffered groups
    __shared__ float dlds[NEXP];

    const int tid  = threadIdx.x;
    const int lane = tid & 63;
    const int l15  = lane & 15;
    const int l4   = lane >> 4;
    const int wv   = tid >> 6;
    const int tok0 = blockIdx.x * TB + wv * 16;

    if (tid < NEXP) dlds[tid] = 0.0f;

    // A-side: lane's fragment k-range is its own contiguous 32B of token row l15
    const float* xr = x + (size_t)(tok0 + l15) * DIM + l4 * 8;

    f32x4 acc[4];
#pragma unroll
    for (int ni = 0; ni < 4; ++ni) acc[ni] = (f32x4){0.f, 0.f, 0.f, 0.f};

    // stage 2-chunk group g into LDS buffer bsel (6 x 4KB shots, linear dest)
    auto stage = [&](int bsel, int g) {
        const char* src = (const char*)wf + (size_t)g * GRP_BYTES + tid * 16;
        char* dst = (char*)&Blds[bsel][0][0] + tid * 16;
#pragma unroll
        for (int s = 0; s < 6; ++s)
            GLDS16(src + s * 4096, dst + s * 4096);
    };

    auto mfma6 = [&](const bf16x8* B, const bf16x8& Ah, const bf16x8& Am,
                     const bf16x8& Al) {
#pragma unroll
        for (int ni = 0; ni < 4; ++ni) {
            f32x4 a = acc[ni];
            a = __builtin_amdgcn_mfma_f32_16x16x32_bf16(Ah, B[ni],     a, 0, 0, 0);
            a = __builtin_amdgcn_mfma_f32_16x16x32_bf16(Ah, B[4 + ni], a, 0, 0, 0);
            a = __builtin_amdgcn_mfma_f32_16x16x32_bf16(Am, B[ni],     a, 0, 0, 0);
            a = __builtin_amdgcn_mfma_f32_16x16x32_bf16(Ah, B[8 + ni], a, 0, 0, 0);
            a = __builtin_amdgcn_mfma_f32_16x16x32_bf16(Am, B[4 + ni], a, 0, 0, 0);
            a = __builtin_amdgcn_mfma_f32_16x16x32_bf16(Al, B[ni],     a, 0, 0, 0);
            acc[ni] = a;
        }
    };

#define LOADX(XA, XB, c) { XA = *(const float4*)(xr + (size_t)(c) * KC);      \
                           XB = *(const float4*)(xr + (size_t)(c) * KC + 4); }
// one chunk: read 12 B-frags from LDS, split x, prefetch x 4 ahead, MFMA
#define CHUNK(XA, XB, bsel, cc, c) {                                          \
        const bf16x8* lb = &Blds[bsel][cc][0];                                \
        bf16x8 Bf[CH_FRAGS];                                                  \
        _Pragma("unroll")                                                     \
        for (int f = 0; f < CH_FRAGS; ++f) Bf[f] = lb[f * 64 + lane];         \
        bf16x8 Ah, Am, Al; split8(XA, XB, Ah, Am, Al);                        \
        if ((c) + 4 < NC) LOADX(XA, XB, (c) + 4);                             \
        mfma6(Bf, Ah, Am, Al); }

    float4 x0a, x0b, x1a, x1b, x2a, x2b, x3a, x3b;
    LOADX(x0a, x0b, 0) LOADX(x1a, x1b, 1) LOADX(x2a, x2b, 2) LOADX(x3a, x3b, 3)
    stage(0, 0);
    __syncthreads();

    for (int g = 0; g < NG; g += 2) {
        // group g (chunks 2g, 2g+1) from buf0; stage group g+1 into buf1
        if (g + 1 < NG) stage(1, g + 1);
        CHUNK(x0a, x0b, 0, 0, 2 * g)
        CHUNK(x1a, x1b, 0, 1, 2 * g + 1)
        __syncthreads();
        // group g+1 from buf1; stage group g+2 into buf0
        if (g + 2 < NG) stage(0, g + 2);
        CHUNK(x2a, x2b, 1, 0, 2 * g + 2)
        CHUNK(x3a, x3b, 1, 1, 2 * g + 3)
        __syncthreads();
    }

    // epilogue: token t = tok0 + 4*l4 + r, experts e = 16*ni + l15
    float bias[4];
#pragma unroll
    for (int ni = 0; ni < 4; ++ni) bias[ni] = b[ni * 16 + l15];

#pragma unroll
    for (int r = 0; r < 4; ++r) {
        const float v0 = acc[0][r] + bias[0];
        const float v1 = acc[1][r] + bias[1];
        const float v2 = acc[2][r] + bias[2];
        const float v3 = acc[3][r] + bias[3];

        // lane-local argmax (ascending e => first-index ties)
        float lm = v0; int le = l15;
        if (v1 > lm) { lm = v1; le = l15 + 16; }
        if (v2 > lm) { lm = v2; le = l15 + 32; }
        if (v3 > lm) { lm = v3; le = l15 + 48; }
        // 16-lane group reduce (same token), first-index on ties
#pragma unroll
        for (int off = 1; off < 16; off <<= 1) {
            const float om = __shfl_xor(lm, off);
            const int   oe = __shfl_xor(le, off);
            if (om > lm || (om == lm && oe < le)) { lm = om; le = oe; }
        }
        float s = __expf(v0 - lm) + __expf(v1 - lm) +
                  __expf(v2 - lm) + __expf(v3 - lm);
#pragma unroll
        for (int off = 1; off < 16; off <<= 1) s += __shfl_xor(s, off);
        const float g = 1.0f / s;            // top-1 gate = exp(0)/sum

        const int t = tok0 + 4 * l4 + r;
        float* orow = out + (size_t)t * NEXP + l15;
        orow[0]  = (le == l15     ) ? g : 0.0f;
        orow[16] = (le == l15 + 16) ? g : 0.0f;
        orow[32] = (le == l15 + 32) ? g : 0.0f;
        orow[48] = (le == l15 + 48) ? g : 0.0f;
        if (l15 == 0) atomicAdd(&dlds[le], g);
    }

    __syncthreads();
    if (tid < NEXP) atomicAdd(&denom[tid], dlds[tid]);
}

// out[n,e] *= capacity / (denom[e] + eps); zeros stay zero (branch-free)
__global__ __launch_bounds__(256)
void scale_kernel(float* __restrict__ out, const float* __restrict__ denom)
{
    __shared__ float sc[NEXP];
    if (threadIdx.x < NEXP)
        sc[threadIdx.x] = (float)NTOK / (denom[threadIdx.x] + 1e-6f);
    __syncthreads();

    const size_t i = (size_t)blockIdx.x * blockDim.x + threadIdx.x; // float4 idx
    float4 v = ((const float4*)out)[i];
    const int e0 = (int)((i * 4) & (NEXP - 1));
    v.x *= sc[e0]; v.y *= sc[e0 + 1]; v.z *= sc[e0 + 2]; v.w *= sc[e0 + 3];
    ((float4*)out)[i] = v;
}

extern "C" void kernel_launch(void* const* d_in, const int* in_sizes, int n_in,
                              void* d_out, int out_size, void* d_ws, size_t ws_size,
                              hipStream_t stream) {
    const float* x = (const float*)d_in[0];
    const float* w = (const float*)d_in[1];
    const float* b = (const float*)d_in[2];
    float*  out   = (float*)d_out;
    float*  denom = (float*)d_ws;                               // 64 floats
    bf16x8* wf    = (bf16x8*)((char*)d_ws + WFOFF);             // 768 KB frags

    zero_denom_kernel<<<1, NEXP, 0, stream>>>(denom);
    wsplit_kernel<<<64, 256, 0, stream>>>(w, wf);               // stream-ordered
    gate_kernel<<<NBLK, 256, 0, stream>>>(x, wf, b, out, denom);
    scale_kernel<<<(NTOK * NEXP / 4) / 256, 256, 0, stream>>>(out, denom);
}

// Round 10
// 81.459 us; speedup vs baseline: 6.0939x; 1.0091x over previous
//
#include <hip/hip_runtime.h>
#include <hip/hip_bf16.h>

#define DIM   2048
#define NEXP  64
#define NTOK  32768
#define KC    32               // k per chunk = one MFMA k-step
#define NC    (DIM / KC)       // 64 chunks
#define TB    128              // tokens per block (4 waves x 32)
#define NBLK  (NTOK / TB)      // 256 blocks = 1/CU
#define NSLOT 5                // LDS pipeline depth (stage 4 ahead)
#define BB    12288            // B bytes per chunk (12 frags x 64 lanes x 16B)
#define XB    16384            // x bytes per chunk (128 tok x 128B)
#define SLOTB (BB + XB)        // 28672 B per slot; 5 slots = 140 KB
#define WFOFF 1024             // byte offset of w-fragments inside d_ws

typedef __attribute__((ext_vector_type(8))) short bf16x8;
typedef __attribute__((ext_vector_type(4))) float f32x4;

typedef __attribute__((address_space(1))) const void gvoid_t;
typedef __attribute__((address_space(3))) void lvoid_t;
#define GLDS16(g, l) __builtin_amdgcn_global_load_lds((gvoid_t*)(g), (lvoid_t*)(l), 16, 0, 0)

// RNE fp32 -> bf16; returns fp32 value of the bf16 (splits are exact diffs)
__device__ __forceinline__ float rne_split(float v, short& h) {
    __hip_bfloat16 hb = __float2bfloat16(v);
    h = __builtin_bit_cast(short, hb);
    return __bfloat162float(hb);
}

__device__ __forceinline__ void split8(const float4& a, const float4& b,
                                       bf16x8& H, bf16x8& M, bf16x8& L) {
    const float vs[8] = {a.x, a.y, a.z, a.w, b.x, b.y, b.z, b.w};
#pragma unroll
    for (int j = 0; j < 8; ++j) {
        short h, m, l;
        const float fh = rne_split(vs[j], h);
        const float e1 = vs[j] - fh;            // exact
        const float fm = rne_split(e1, m);
        const float e2 = e1 - fm;               // exact
        rne_split(e2, l);
        H[j] = h; M[j] = m; L[j] = l;
    }
}

// Pre-split w into CHUNK-MAJOR fragment order (12 KB/chunk); also zero denom.
// unit idx = ((ks*3 + lvl)*4 + ni)*64 + lane covers
// B[k = ks*32 + 8*(lane>>4) + j][n = ni*16 + (lane&15)].
__global__ __launch_bounds__(256)
void wsplit_kernel(const float* __restrict__ w, bf16x8* __restrict__ wf,
                   float* __restrict__ denom) {
    if (blockIdx.x == 0 && threadIdx.x < NEXP) denom[threadIdx.x] = 0.0f;
    const int tid  = blockIdx.x * 256 + threadIdx.x;   // 16384 threads
    const int lane = tid & 63;
    const int ni   = (tid >> 6) & 3;
    const int ks   = tid >> 8;
    const int n    = ni * 16 + (lane & 15);
    const int k0   = ks * KC + (lane >> 4) * 8;
    bf16x8 H, M, L;
#pragma unroll
    for (int j = 0; j < 8; ++j) {
        const float v = w[(size_t)(k0 + j) * NEXP + n];
        short h, m, l;
        const float fh = rne_split(v, h);
        const float e1 = v - fh;
        const float fm = rne_split(e1, m);
        rne_split(e1 - fm, l);
        H[j] = h; M[j] = m; L[j] = l;
    }
    wf[((size_t)(ks * 3 + 0) * 4 + ni) * 64 + lane] = H;
    wf[((size_t)(ks * 3 + 1) * 4 + ni) * 64 + lane] = M;
    wf[((size_t)(ks * 3 + 2) * 4 + ni) * 64 + lane] = L;
}

__global__ __launch_bounds__(256, 1)
void gate_kernel(const float* __restrict__ x, const bf16x8* __restrict__ wf,
                 const float* __restrict__ b, float* __restrict__ out,
                 float* __restrict__ denom)
{
    __shared__ __align__(16) char slab[NSLOT * SLOTB];   // 140 KB
    __shared__ float dlds[NEXP];

    const int tid  = threadIdx.x;
    const int lane = tid & 63;
    const int l15  = lane & 15;
    const int l4   = lane >> 4;
    const int wv   = tid >> 6;
    const int tok0 = blockIdx.x * TB;

    if (tid < NEXP) dlds[tid] = 0.0f;

    float bias[4];
#pragma unroll
    for (int ni = 0; ni < 4; ++ni) bias[ni] = b[ni * 16 + l15];

    // x ds_read unit indices (rotated layout, conflict-free): lane reads
    // token row bl, float4 j at unit bl*8 + ((j + bl) & 7)
    const int bl0 = wv * 32 + l15;           // m-tile 0 block-local token
    const int bl1 = bl0 + 16;                // m-tile 1
    const int j0  = l4 * 2;
    const int xu00 = bl0 * 8 + ((j0 + bl0) & 7);
    const int xu01 = bl0 * 8 + ((j0 + 1 + bl0) & 7);
    const int xu10 = bl1 * 8 + ((j0 + bl1) & 7);
    const int xu11 = bl1 * 8 + ((j0 + 1 + bl1) & 7);

    // stage chunk c into slot: B linear (3 shots), x rotated-source (4 shots)
    auto stage = [&](int slot, int c) {
        char* sb = slab + slot * SLOTB;
        const char* bsrc = (const char*)wf + (size_t)c * BB + tid * 16;
        GLDS16(bsrc,        sb + tid * 16);
        GLDS16(bsrc + 4096, sb + tid * 16 + 4096);
        GLDS16(bsrc + 8192, sb + tid * 16 + 8192);
        char* xb = sb + BB;
#pragma unroll
        for (int s = 0; s < 4; ++s) {
            const int u = s * 256 + tid;
            const int t = u >> 3;
            const int j = ((u & 7) - t) & 7;
            // dest = uniform + lane*16 (linear); source carries the rotation
            GLDS16(x + (size_t)(tok0 + t) * DIM + c * KC + j * 4, xb + u * 16);
        }
    };

    f32x4 acc[2][4];
#pragma unroll
    for (int mi = 0; mi < 2; ++mi)
#pragma unroll
        for (int ni = 0; ni < 4; ++ni) acc[mi][ni] = (f32x4){0.f, 0.f, 0.f, 0.f};

    // prologue: fill 4 slots (28 VMEM ops outstanding)
    stage(0, 0); stage(1, 1); stage(2, 2); stage(3, 3);

    int scomp = 0, sstage = 4;
    for (int c = 0; c < NC; ++c) {
        // wait for chunk c's 7 shots (newest 21 = chunks c+1..c+3 may remain)
        asm volatile("s_waitcnt vmcnt(21)" ::: "memory");
        __builtin_amdgcn_s_barrier();
        __builtin_amdgcn_sched_barrier(0);

        const char* sb = slab + scomp * SLOTB;
        const bf16x8* bl = (const bf16x8*)sb;
        bf16x8 Bf[12];
#pragma unroll
        for (int f = 0; f < 12; ++f) Bf[f] = bl[f * 64 + lane];

        const float4* xun = (const float4*)(sb + BB);
        const float4 xa0 = xun[xu00], xb0 = xun[xu01];
        const float4 xa1 = xun[xu10], xb1 = xun[xu11];

        bf16x8 Ah0, Am0, Al0, Ah1, Am1, Al1;
        split8(xa0, xb0, Ah0, Am0, Al0);
        split8(xa1, xb1, Ah1, Am1, Al1);

#pragma unroll
        for (int ni = 0; ni < 4; ++ni) {
            f32x4 a0 = acc[0][ni], a1 = acc[1][ni];
            a0 = __builtin_amdgcn_mfma_f32_16x16x32_bf16(Ah0, Bf[ni],     a0, 0, 0, 0);
            a1 = __builtin_amdgcn_mfma_f32_16x16x32_bf16(Ah1, Bf[ni],     a1, 0, 0, 0);
            a0 = __builtin_amdgcn_mfma_f32_16x16x32_bf16(Ah0, Bf[4 + ni], a0, 0, 0, 0);
            a1 = __builtin_amdgcn_mfma_f32_16x16x32_bf16(Ah1, Bf[4 + ni], a1, 0, 0, 0);
            a0 = __builtin_amdgcn_mfma_f32_16x16x32_bf16(Am0, Bf[ni],     a0, 0, 0, 0);
            a1 = __builtin_amdgcn_mfma_f32_16x16x32_bf16(Am1, Bf[ni],     a1, 0, 0, 0);
            a0 = __builtin_amdgcn_mfma_f32_16x16x32_bf16(Ah0, Bf[8 + ni], a0, 0, 0, 0);
            a1 = __builtin_amdgcn_mfma_f32_16x16x32_bf16(Ah1, Bf[8 + ni], a1, 0, 0, 0);
            a0 = __builtin_amdgcn_mfma_f32_16x16x32_bf16(Am0, Bf[4 + ni], a0, 0, 0, 0);
            a1 = __builtin_amdgcn_mfma_f32_16x16x32_bf16(Am1, Bf[4 + ni], a1, 0, 0, 0);
            a0 = __builtin_amdgcn_mfma_f32_16x16x32_bf16(Al0, Bf[ni],     a0, 0, 0, 0);
            a1 = __builtin_amdgcn_mfma_f32_16x16x32_bf16(Al1, Bf[ni],     a1, 0, 0, 0);
            acc[0][ni] = a0; acc[1][ni] = a1;
        }

        // stage AFTER compute: barrier(c) guarantees all waves done with the
        // slot being overwritten (chunk c-1). Tail: dummy re-stage of chunk 63
        // keeps vmcnt arithmetic uniform (never read).
        const int cn = (c + 4 < NC) ? c + 4 : NC - 1;
        stage(sstage, cn);

        if (++scomp == NSLOT) scomp = 0;
        if (++sstage == NSLOT) sstage = 0;
    }

    __syncthreads();   // drain tail stages; dlds zero visible

    // epilogue: token t = tok0 + wv*32 + mi*16 + 4*l4 + r, expert e = ni*16+l15
#pragma unroll
    for (int mi = 0; mi < 2; ++mi)
#pragma unroll
        for (int r = 0; r < 4; ++r) {
            const float v0 = acc[mi][0][r] + bias[0];
            const float v1 = acc[mi][1][r] + bias[1];
            const float v2 = acc[mi][2][r] + bias[2];
            const float v3 = acc[mi][3][r] + bias[3];

            // lane-local argmax (ascending e => first-index ties)
            float lm = v0; int le = l15;
            if (v1 > lm) { lm = v1; le = l15 + 16; }
            if (v2 > lm) { lm = v2; le = l15 + 32; }
            if (v3 > lm) { lm = v3; le = l15 + 48; }
#pragma unroll
            for (int off = 1; off < 16; off <<= 1) {
                const float om = __shfl_xor(lm, off);
                const int   oe = __shfl_xor(le, off);
                if (om > lm || (om == lm && oe < le)) { lm = om; le = oe; }
            }
            float s = __expf(v0 - lm) + __expf(v1 - lm) +
                      __expf(v2 - lm) + __expf(v3 - lm);
#pragma unroll
            for (int off = 1; off < 16; off <<= 1) s += __shfl_xor(s, off);
            const float g = 1.0f / s;            // top-1 gate = exp(0)/sum

            const int t = tok0 + wv * 32 + mi * 16 + 4 * l4 + r;
            float* orow = out + (size_t)t * NEXP + l15;
            orow[0]  = (le == l15     ) ? g : 0.0f;
            orow[16] = (le == l15 + 16) ? g : 0.0f;
            orow[32] = (le == l15 + 32) ? g : 0.0f;
            orow[48] = (le == l15 + 48) ? g : 0.0f;
            if (l15 == 0) atomicAdd(&dlds[le], g);
        }

    __syncthreads();
    if (tid < NEXP) atomicAdd(&denom[tid], dlds[tid]);
}

// out[n,e] *= capacity / (denom[e] + eps); zeros stay zero (branch-free)
__global__ __launch_bounds__(256)
void scale_kernel(float* __restrict__ out, const float* __restrict__ denom)
{
    __shared__ float sc[NEXP];
    if (threadIdx.x < NEXP)
        sc[threadIdx.x] = (float)NTOK / (denom[threadIdx.x] + 1e-6f);
    __syncthreads();

    const size_t i = (size_t)blockIdx.x * blockDim.x + threadIdx.x; // float4 idx
    float4 v = ((const float4*)out)[i];
    const int e0 = (int)((i * 4) & (NEXP - 1));
    v.x *= sc[e0]; v.y *= sc[e0 + 1]; v.z *= sc[e0 + 2]; v.w *= sc[e0 + 3];
    ((float4*)out)[i] = v;
}

extern "C" void kernel_launch(void* const* d_in, const int* in_sizes, int n_in,
                              void* d_out, int out_size, void* d_ws, size_t ws_size,
                              hipStream_t stream) {
    const float* x = (const float*)d_in[0];
    const float* w = (const float*)d_in[1];
    const float* b = (const float*)d_in[2];
    float*  out   = (float*)d_out;
    float*  denom = (float*)d_ws;                               // 64 floats
    bf16x8* wf    = (bf16x8*)((char*)d_ws + WFOFF);             // 768 KB frags

    wsplit_kernel<<<64, 256, 0, stream>>>(w, wf, denom);        // also zeroes denom
    gate_kernel<<<NBLK, 256, 0, stream>>>(x, wf, b, out, denom);
    scale_kernel<<<(NTOK * NEXP / 4) / 256, 256, 0, stream>>>(out, denom);
}